// Round 7
// baseline (61.846 us; speedup 1.0000x reference)
//
#include <hip/hip_runtime.h>

// Bahdanau multi-head attention, fp32 in/out, B=2 L=128 D=512 H=8 dh=64.
// R7: 3 launches. Kernel 1 fuses QKV projection + additive-feature GEMM:
//     block = (mat,b,l-half,head) computes Q/K head-tile (K=512) into LDS,
//     then the qf/kf strip [64x512] (K=64) straight from LDS. V = phase-1
//     only. attn + out kernels unchanged from R6 (measured good).

#define NHEADS 8
#define DH 64
#define DM 512
#define BB 2
#define LQL 128
#define LKL 128
#define QPB 4

typedef _Float16 v8h __attribute__((ext_vector_type(8)));
typedef float v4f __attribute__((ext_vector_type(4)));

static __device__ __forceinline__ float fexp2(float x) { return __builtin_amdgcn_exp2f(x); }
static __device__ __forceinline__ float frcp(float x)  { return __builtin_amdgcn_rcpf(x); }

static __device__ __forceinline__ v8h cvt8(const float4 a, const float4 b) {
    v8h h;
    h[0] = (_Float16)a.x; h[1] = (_Float16)a.y; h[2] = (_Float16)a.z; h[3] = (_Float16)a.w;
    h[4] = (_Float16)b.x; h[5] = (_Float16)b.y; h[6] = (_Float16)b.z; h[7] = (_Float16)b.w;
    return h;
}

// ---- Kernel 1: fused QKV projection + qf/kf features ------------------------
// 96 blocks x 256 thr. bid -> mat (0:Q->qf, 1:K->kf, 2:V), b, l-half, head/ct.
__global__ __launch_bounds__(256) void qkvfeat_mfma(
    const float* __restrict__ xq, const float* __restrict__ xk, const float* __restrict__ xv,
    const float* __restrict__ Wq, const float* __restrict__ Wk, const float* __restrict__ Wv,
    const float* __restrict__ Wqa, const float* __restrict__ Wka,
    const int* __restrict__ vl,
    float* __restrict__ V, float* __restrict__ qf, float* __restrict__ kf)
{
    const int bid = blockIdx.x;          // 0..95
    const int mat = bid >> 5;
    const int sub = bid & 31;
    const int b  = sub >> 4;
    const int hc = (sub >> 1) & 7;       // head (mat<2) or col-tile (mat=2)
    const int lh = sub & 1;
    if (mat >= 1 && lh * 64 >= vl[b]) return;    // masked K/V row-halves

    const float* X = mat == 0 ? xq : (mat == 1 ? xk : xv);
    const float* W = mat == 0 ? Wq : (mat == 1 ? Wk : Wv);

    __shared__ _Float16 As[64][40];
    __shared__ _Float16 Ws[64][40];
    __shared__ _Float16 Qt[64][72];      // phase-1 result tile (l x dh), fp16
    __shared__ _Float16 W2[64][72];      // phase-2 Wa tile (f x dh), fp16

    const int tid = threadIdx.x, wave = tid >> 6, lane = tid & 63;
    const int srow = tid >> 2, sseg = tid & 3;
    const int fr = lane & 15, fg = (lane >> 4) * 8;
    const int xrow0 = b * LQL + lh * 64;
    const int wrow0 = hc * 64;

    // Phase 1: T[64x64] = X[xrow0..+64] @ W[wrow0..+64]^T, K=512
    v4f acc[4] = {};
    for (int k0 = 0; k0 < DM; k0 += 32) {
        const float4* ap = (const float4*)(X + (size_t)(xrow0 + srow) * DM + k0 + sseg * 8);
        const float4 a0 = ap[0], a1 = ap[1];
        const float4* wp = (const float4*)(W + (size_t)(wrow0 + srow) * DM + k0 + sseg * 8);
        const float4 w0 = wp[0], w1 = wp[1];
        __syncthreads();
        *(v8h*)&As[srow][sseg * 8] = cvt8(a0, a1);
        *(v8h*)&Ws[srow][sseg * 8] = cvt8(w0, w1);
        __syncthreads();
        const v8h af = *(const v8h*)&As[wave * 16 + fr][fg];
        #pragma unroll
        for (int sn = 0; sn < 4; ++sn) {
            const v8h bf = *(const v8h*)&Ws[sn * 16 + fr][fg];
            acc[sn] = __builtin_amdgcn_mfma_f32_16x16x32_f16(af, bf, acc[sn], 0, 0, 0);
        }
    }

    if (mat == 2) {                      // V: store fp32, done
        #pragma unroll
        for (int sn = 0; sn < 4; ++sn)
            #pragma unroll
            for (int rg = 0; rg < 4; ++rg) {
                const int row = xrow0 + wave * 16 + (lane >> 4) * 4 + rg;
                const int col = hc * 64 + sn * 16 + fr;
                V[(size_t)row * DM + col] = acc[sn][rg];
            }
        return;
    }

    // park T in LDS as fp16 (same precision path as the old Qh/Kh roundtrip)
    #pragma unroll
    for (int sn = 0; sn < 4; ++sn)
        #pragma unroll
        for (int rg = 0; rg < 4; ++rg)
            Qt[wave * 16 + (lane >> 4) * 4 + rg][sn * 16 + fr] = (_Float16)acc[sn][rg];

    // Phase 2: F[64 x 512] = T @ Wa^T, Wa = Wqa/Wka [512][64], K=64
    const float* Wa = mat == 0 ? Wqa : Wka;
    float* C = mat == 0 ? qf : kf;
    const int crow0 = (b * NHEADS + hc) * LQL + lh * 64;
    const int r2 = tid >> 2, cs = (tid & 3) * 16;
    for (int ft = 0; ft < 8; ++ft) {
        const float4* wp = (const float4*)(Wa + (size_t)(ft * 64 + r2) * DH + cs);
        const float4 w0 = wp[0], w1 = wp[1], w2 = wp[2], w3 = wp[3];
        __syncthreads();                 // prev iter done reading W2 (iter0: Qt write)
        *(v8h*)&W2[r2][cs]     = cvt8(w0, w1);
        *(v8h*)&W2[r2][cs + 8] = cvt8(w2, w3);
        __syncthreads();
        v4f fa[4] = {};
        #pragma unroll
        for (int kk = 0; kk < 2; ++kk) {
            const v8h af = *(const v8h*)&Qt[wave * 16 + fr][kk * 32 + fg];
            #pragma unroll
            for (int sn = 0; sn < 4; ++sn) {
                const v8h bf = *(const v8h*)&W2[sn * 16 + fr][kk * 32 + fg];
                fa[sn] = __builtin_amdgcn_mfma_f32_16x16x32_f16(af, bf, fa[sn], 0, 0, 0);
            }
        }
        #pragma unroll
        for (int sn = 0; sn < 4; ++sn)
            #pragma unroll
            for (int rg = 0; rg < 4; ++rg) {
                const int row = crow0 + wave * 16 + (lane >> 4) * 4 + rg;
                const int col = ft * 64 + sn * 16 + fr;
                C[(size_t)row * DM + col] = fa[sn][rg];
            }
    }
}

// ---- Kernel 2: fused score + masked softmax + PV (fp32) — unchanged R6 -----
__global__ __launch_bounds__(512, 2) void attn_kernel(
    const float* __restrict__ qf, const float* __restrict__ kf,
    const float* __restrict__ V, const float* __restrict__ wv_a,
    const int* __restrict__ vl, _Float16* __restrict__ interh)
{
    __shared__ float s_qf2[QPB][DM];
    __shared__ float s_wv2[DM];
    __shared__ float s_part[4][QPB][132];
    __shared__ float s_attn[QPB][LKL];
    __shared__ float s_pv[2][QPB][DH];

    const float C2 = 2.8853900818f;      // 2*log2(e)
    const float LOG2E = 1.4426950409f;

    const int bid = blockIdx.x;
    const int b  = bid >> 8;
    const int h  = (bid >> 5) & 7;
    const int qt = bid & 31;
    const int qbase = qt * QPB;
    const int bh = b * NHEADS + h;
    const int t = threadIdx.x;
    const int Lv = vl[b];

    {   // stage qf (pre-scaled by 2log2e) and wv (pre-scaled by -2)
        const int r = t >> 7, cc = (t & 127) * 4;
        const float4 v = *(const float4*)(qf + ((size_t)(bh * LQL + qbase + r)) * DM + cc);
        s_qf2[r][cc+0] = v.x * C2; s_qf2[r][cc+1] = v.y * C2;
        s_qf2[r][cc+2] = v.z * C2; s_qf2[r][cc+3] = v.w * C2;
        s_wv2[t] = wv_a[t] * -2.0f;
    }
    __syncthreads();

    const int w = t >> 6, lane = t & 63;
    const int k  = w * 16 + (lane & 15); // wave covers 16 consecutive k
    const int fq = lane >> 4;
    float acc[QPB] = {};
    if (k < Lv) {
        const float* kp = kf + ((size_t)(bh * LKL + k)) * DM + fq * 128;
        float4 kA = *(const float4*)kp;
        float4 kB = *(const float4*)(kp + 4);
        #pragma unroll 1
        for (int it = 0; it < 16; ++it) {
            float4 nA, nB;
            if (it < 15) { nA = *(const float4*)(kp + 8); nB = *(const float4*)(kp + 12); }
            else         { nA = kA; nB = kB; }
            const int f0 = fq * 128 + it * 8;
            const float4 w0 = *(const float4*)&s_wv2[f0];
            const float4 w1 = *(const float4*)&s_wv2[f0 + 4];
            #pragma unroll
            for (int q = 0; q < QPB; ++q) {
                const float4 q0 = *(const float4*)&s_qf2[q][f0];
                const float4 q1 = *(const float4*)&s_qf2[q][f0 + 4];
                float a = acc[q];
                a = fmaf(w0.x, frcp(fexp2(fmaf(kA.x, C2, q0.x)) + 1.f), a);
                a = fmaf(w0.y, frcp(fexp2(fmaf(kA.y, C2, q0.y)) + 1.f), a);
                a = fmaf(w0.z, frcp(fexp2(fmaf(kA.z, C2, q0.z)) + 1.f), a);
                a = fmaf(w0.w, frcp(fexp2(fmaf(kA.w, C2, q0.w)) + 1.f), a);
                a = fmaf(w1.x, frcp(fexp2(fmaf(kB.x, C2, q1.x)) + 1.f), a);
                a = fmaf(w1.y, frcp(fexp2(fmaf(kB.y, C2, q1.y)) + 1.f), a);
                a = fmaf(w1.z, frcp(fexp2(fmaf(kB.z, C2, q1.z)) + 1.f), a);
                a = fmaf(w1.w, frcp(fexp2(fmaf(kB.w, C2, q1.w)) + 1.f), a);
                acc[q] = a;
            }
            kA = nA; kB = nB; kp += 8;
        }
    }
    #pragma unroll
    for (int q = 0; q < QPB; ++q) s_part[fq][q][k] = acc[q];
    __syncthreads();

    if (t < 64 * QPB) {   // masked softmax: wave = q-row; lane covers k, k+64
        const int q = t >> 6, ln = t & 63;
        float v0 = -3.0e38f, v1 = -3.0e38f;
        if (ln < Lv)
            v0 = s_part[0][q][ln] + s_part[1][q][ln]
               + s_part[2][q][ln] + s_part[3][q][ln];
        if (ln + 64 < Lv)
            v1 = s_part[0][q][ln+64] + s_part[1][q][ln+64]
               + s_part[2][q][ln+64] + s_part[3][q][ln+64];
        float m = fmaxf(v0, v1);
        #pragma unroll
        for (int off = 32; off; off >>= 1) m = fmaxf(m, __shfl_xor(m, off, 64));
        const float e0 = fexp2((v0 - m) * LOG2E);
        const float e1 = fexp2((v1 - m) * LOG2E);
        float s = e0 + e1;
        #pragma unroll
        for (int off = 32; off; off >>= 1) s += __shfl_xor(s, off, 64);
        const float inv = frcp(s);
        s_attn[q][ln]      = e0 * inv;
        s_attn[q][ln + 64] = e1 * inv;
    }
    __syncthreads();

    {   // PV: thread (kh = t>>8, q = (t>>6)&3, d = t&63); only k < Lv
        const int d = t & 63, q = (t >> 6) & 3, kh = t >> 8;
        const float* vb = V + ((size_t)(b * LKL + kh * 64)) * DM + h * DH + d;
        int kmax = Lv - kh * 64;
        kmax = kmax < 0 ? 0 : (kmax > 64 ? 64 : kmax);
        float a0 = 0.f, a1 = 0.f, a2 = 0.f, a3 = 0.f;
        int kk = 0;
        for (; kk + 4 <= kmax; kk += 4) {
            a0 += s_attn[q][kh*64 + kk+0] * vb[(size_t)(kk+0) * DM];
            a1 += s_attn[q][kh*64 + kk+1] * vb[(size_t)(kk+1) * DM];
            a2 += s_attn[q][kh*64 + kk+2] * vb[(size_t)(kk+2) * DM];
            a3 += s_attn[q][kh*64 + kk+3] * vb[(size_t)(kk+3) * DM];
        }
        for (; kk < kmax; ++kk) a0 += s_attn[q][kh*64 + kk] * vb[(size_t)kk * DM];
        s_pv[kh][q][d] = (a0 + a1) + (a2 + a3);
    }
    __syncthreads();
    if (t < 64 * QPB) {
        const int q = t >> 6, d = t & 63;
        interh[((size_t)(b * LQL + qbase + q)) * DM + h * DH + d] =
            (_Float16)(s_pv[0][q][d] + s_pv[1][q][d]);
    }
}

// ---- Kernel 3: out = inter @ Wo^T via MFMA (fp32 out) — unchanged R6 -------
__global__ __launch_bounds__(256) void out_mfma(
    const _Float16* __restrict__ interh, const float* __restrict__ Wo,
    float* __restrict__ out)
{
    const int bm0 = blockIdx.y * 64, bn0 = blockIdx.x * 64;
    __shared__ _Float16 As[64][40];
    __shared__ _Float16 Ws[64][40];
    const int tid = threadIdx.x, wave = tid >> 6, lane = tid & 63;
    const int srow = tid >> 2, sseg = tid & 3;
    const int fr = lane & 15, fg = (lane >> 4) * 8;

    v4f acc[4] = {};
    for (int k0 = 0; k0 < DM; k0 += 32) {
        const v8h ha = *(const v8h*)(interh + (size_t)(bm0 + srow) * DM + k0 + sseg * 8);
        const float4* wp = (const float4*)(Wo + (size_t)(bn0 + srow) * DM + k0 + sseg * 8);
        const float4 w0 = wp[0], w1 = wp[1];
        __syncthreads();
        *(v8h*)&As[srow][sseg * 8] = ha;
        *(v8h*)&Ws[srow][sseg * 8] = cvt8(w0, w1);
        __syncthreads();
        const v8h af = *(const v8h*)&As[wave * 16 + fr][fg];
        #pragma unroll
        for (int sn = 0; sn < 4; ++sn) {
            const v8h bf = *(const v8h*)&Ws[sn * 16 + fr][fg];
            acc[sn] = __builtin_amdgcn_mfma_f32_16x16x32_f16(af, bf, acc[sn], 0, 0, 0);
        }
    }
    #pragma unroll
    for (int sn = 0; sn < 4; ++sn)
        #pragma unroll
        for (int rg = 0; rg < 4; ++rg) {
            const int row = bm0 + wave * 16 + (lane >> 4) * 4 + rg;
            const int col = bn0 + sn * 16 + fr;
            out[(size_t)row * DM + col] = acc[sn][rg];
        }
}

extern "C" void kernel_launch(void* const* d_in, const int* in_sizes, int n_in,
                              void* d_out, int out_size, void* d_ws, size_t ws_size,
                              hipStream_t stream)
{
    const float* xq   = (const float*)d_in[0];
    const float* xk   = (const float*)d_in[1];
    const float* xv   = (const float*)d_in[2];
    const int*   vl   = (const int*)d_in[3];
    const float* Wq   = (const float*)d_in[4];
    const float* Wk   = (const float*)d_in[5];
    const float* Wv   = (const float*)d_in[6];
    const float* Wo   = (const float*)d_in[7];
    const float* Wqa  = (const float*)d_in[8];
    const float* Wka  = (const float*)d_in[9];
    const float* wv_a = (const float*)d_in[10];
    float* out = (float*)d_out;

    // ws carve (bytes): V 512K | qf 4M | kf 4M | interh 256K  (8.75 MB)
    char* base = (char*)d_ws;
    float*    V      = (float*)   (base);
    float*    qf     = (float*)   (base + 524288);
    float*    kf     = (float*)   (base + 4718592);
    _Float16* interh = (_Float16*)(base + 8912896);

    qkvfeat_mfma<<<dim3(96), dim3(256), 0, stream>>>(
        xq, xk, xv, Wq, Wk, Wv, Wqa, Wka, vl, V, qf, kf);
    attn_kernel<<<dim3(512), dim3(512), 0, stream>>>(
        qf, kf, V, wv_a, vl, interh);
    out_mfma<<<dim3(8, 4), dim3(256), 0, stream>>>(interh, Wo, out);
}

// Round 8
// 56.745 us; speedup vs baseline: 1.0899x; 1.0899x over previous
//
#include <hip/hip_runtime.h>

// Bahdanau multi-head attention, fp32 in/out, B=2 L=128 D=512 H=8 dh=64.
// R8: exp-factorized score: feat kernel stores eqf=exp2(C2*qf) (f32) and
//     ekf=exp2(C2*kf) (bf16). attn eval = fmaf(wv, rcp(fmaf(ek,eq,1)), acc)
//     -> 2 VALU + 1 trans per eval (was 3+2). Structure unchanged from R7.

#define NHEADS 8
#define DH 64
#define DM 512
#define BB 2
#define LQL 128
#define LKL 128
#define QPB 4

typedef _Float16 v8h __attribute__((ext_vector_type(8)));
typedef float v4f __attribute__((ext_vector_type(4)));

static __device__ __forceinline__ float fexp2(float x) { return __builtin_amdgcn_exp2f(x); }
static __device__ __forceinline__ float frcp(float x)  { return __builtin_amdgcn_rcpf(x); }

static __device__ __forceinline__ v8h cvt8(const float4 a, const float4 b) {
    v8h h;
    h[0] = (_Float16)a.x; h[1] = (_Float16)a.y; h[2] = (_Float16)a.z; h[3] = (_Float16)a.w;
    h[4] = (_Float16)b.x; h[5] = (_Float16)b.y; h[6] = (_Float16)b.z; h[7] = (_Float16)b.w;
    return h;
}

static __device__ __forceinline__ unsigned short f2bf(float x) {   // RTNE
    unsigned int u = __float_as_uint(x);
    u += 0x7FFFu + ((u >> 16) & 1u);
    return (unsigned short)(u >> 16);
}
static __device__ __forceinline__ float bflo(unsigned int u) {
    return __uint_as_float(u << 16);
}
static __device__ __forceinline__ float bfhi(unsigned int u) {
    return __uint_as_float(u & 0xFFFF0000u);
}

// ---- Kernel 1: fused QKV projection + exp'd qf/kf features ------------------
// 96 blocks x 256 thr. bid -> mat (0:Q->eqf, 1:K->ekf, 2:V), b, l-half, head.
__global__ __launch_bounds__(256) void qkvfeat_mfma(
    const float* __restrict__ xq, const float* __restrict__ xk, const float* __restrict__ xv,
    const float* __restrict__ Wq, const float* __restrict__ Wk, const float* __restrict__ Wv,
    const float* __restrict__ Wqa, const float* __restrict__ Wka,
    const int* __restrict__ vl,
    float* __restrict__ V, float* __restrict__ eqf, unsigned short* __restrict__ ekf)
{
    const float C2 = 2.8853900818f;      // 2*log2(e)
    const int bid = blockIdx.x;          // 0..95
    const int mat = bid >> 5;
    const int sub = bid & 31;
    const int b  = sub >> 4;
    const int hc = (sub >> 1) & 7;       // head (mat<2) or col-tile (mat=2)
    const int lh = sub & 1;
    if (mat >= 1 && lh * 64 >= vl[b]) return;    // masked K/V row-halves

    const float* X = mat == 0 ? xq : (mat == 1 ? xk : xv);
    const float* W = mat == 0 ? Wq : (mat == 1 ? Wk : Wv);

    __shared__ _Float16 As[64][40];
    __shared__ _Float16 Ws[64][40];
    __shared__ _Float16 Qt[64][72];      // phase-1 result tile (l x dh), fp16
    __shared__ _Float16 W2[64][72];      // phase-2 Wa tile (f x dh), fp16

    const int tid = threadIdx.x, wave = tid >> 6, lane = tid & 63;
    const int srow = tid >> 2, sseg = tid & 3;
    const int fr = lane & 15, fg = (lane >> 4) * 8;
    const int xrow0 = b * LQL + lh * 64;
    const int wrow0 = hc * 64;

    // Phase 1: T[64x64] = X[xrow0..+64] @ W[wrow0..+64]^T, K=512
    v4f acc[4] = {};
    for (int k0 = 0; k0 < DM; k0 += 32) {
        const float4* ap = (const float4*)(X + (size_t)(xrow0 + srow) * DM + k0 + sseg * 8);
        const float4 a0 = ap[0], a1 = ap[1];
        const float4* wp = (const float4*)(W + (size_t)(wrow0 + srow) * DM + k0 + sseg * 8);
        const float4 w0 = wp[0], w1 = wp[1];
        __syncthreads();
        *(v8h*)&As[srow][sseg * 8] = cvt8(a0, a1);
        *(v8h*)&Ws[srow][sseg * 8] = cvt8(w0, w1);
        __syncthreads();
        const v8h af = *(const v8h*)&As[wave * 16 + fr][fg];
        #pragma unroll
        for (int sn = 0; sn < 4; ++sn) {
            const v8h bf = *(const v8h*)&Ws[sn * 16 + fr][fg];
            acc[sn] = __builtin_amdgcn_mfma_f32_16x16x32_f16(af, bf, acc[sn], 0, 0, 0);
        }
    }

    if (mat == 2) {                      // V: store fp32, done
        #pragma unroll
        for (int sn = 0; sn < 4; ++sn)
            #pragma unroll
            for (int rg = 0; rg < 4; ++rg) {
                const int row = xrow0 + wave * 16 + (lane >> 4) * 4 + rg;
                const int col = hc * 64 + sn * 16 + fr;
                V[(size_t)row * DM + col] = acc[sn][rg];
            }
        return;
    }

    // park T in LDS as fp16 (same precision path as an fp16 global roundtrip)
    #pragma unroll
    for (int sn = 0; sn < 4; ++sn)
        #pragma unroll
        for (int rg = 0; rg < 4; ++rg)
            Qt[wave * 16 + (lane >> 4) * 4 + rg][sn * 16 + fr] = (_Float16)acc[sn][rg];

    // Phase 2: F[64 x 512] = T @ Wa^T, K=64; store exp2(C2*F)
    const float* Wa = mat == 0 ? Wqa : Wka;
    const int crow0 = (b * NHEADS + hc) * LQL + lh * 64;
    const int r2 = tid >> 2, cs = (tid & 3) * 16;
    for (int ft = 0; ft < 8; ++ft) {
        const float4* wp = (const float4*)(Wa + (size_t)(ft * 64 + r2) * DH + cs);
        const float4 w0 = wp[0], w1 = wp[1], w2 = wp[2], w3 = wp[3];
        __syncthreads();                 // prev iter done reading W2 (iter0: Qt write)
        *(v8h*)&W2[r2][cs]     = cvt8(w0, w1);
        *(v8h*)&W2[r2][cs + 8] = cvt8(w2, w3);
        __syncthreads();
        v4f fa[4] = {};
        #pragma unroll
        for (int kk = 0; kk < 2; ++kk) {
            const v8h af = *(const v8h*)&Qt[wave * 16 + fr][kk * 32 + fg];
            #pragma unroll
            for (int sn = 0; sn < 4; ++sn) {
                const v8h bf = *(const v8h*)&W2[sn * 16 + fr][kk * 32 + fg];
                fa[sn] = __builtin_amdgcn_mfma_f32_16x16x32_f16(af, bf, fa[sn], 0, 0, 0);
            }
        }
        #pragma unroll
        for (int sn = 0; sn < 4; ++sn)
            #pragma unroll
            for (int rg = 0; rg < 4; ++rg) {
                const int row = crow0 + wave * 16 + (lane >> 4) * 4 + rg;
                const int col = ft * 64 + sn * 16 + fr;
                const float ev = fexp2(C2 * fa[sn][rg]);
                if (mat == 0) eqf[(size_t)row * DM + col] = ev;
                else          ekf[(size_t)row * DM + col] = f2bf(ev);
            }
    }
}

// ---- Kernel 2: fused score + masked softmax + PV ----------------------------
// 512 blocks (b,h,qtile of 4), 512 thr. Wave w owns k in [w*16,w*16+16),
// lane = (k&15)|(fq<<4). eval: acc += wv2 * rcp(ek*eq + 1).
__global__ __launch_bounds__(512, 2) void attn_kernel(
    const float* __restrict__ eqf, const unsigned short* __restrict__ ekf,
    const float* __restrict__ V, const float* __restrict__ wv_a,
    const int* __restrict__ vl, _Float16* __restrict__ interh)
{
    __shared__ float s_eq[QPB][DM];        // 8 KB (already exp'd)
    __shared__ float s_wv2[DM];            // 2 KB (wv * -2)
    __shared__ float s_part[4][QPB][132];
    __shared__ float s_attn[QPB][LKL];
    __shared__ float s_pv[2][QPB][DH];

    const float LOG2E = 1.4426950409f;

    const int bid = blockIdx.x;
    const int b  = bid >> 8;
    const int h  = (bid >> 5) & 7;
    const int qt = bid & 31;
    const int qbase = qt * QPB;
    const int bh = b * NHEADS + h;
    const int t = threadIdx.x;
    const int Lv = vl[b];

    {   // stage eqf (direct copy) and wv (pre-scaled by -2)
        const int r = t >> 7, cc = (t & 127) * 4;
        *(float4*)&s_eq[r][cc] =
            *(const float4*)(eqf + ((size_t)(bh * LQL + qbase + r)) * DM + cc);
        s_wv2[t] = wv_a[t] * -2.0f;
    }
    __syncthreads();

    const int w = t >> 6, lane = t & 63;
    const int k  = w * 16 + (lane & 15);   // wave covers 16 consecutive k
    const int fq = lane >> 4;
    float acc[QPB] = {};
    if (k < Lv) {
        const unsigned short* kp = ekf + ((size_t)(bh * LKL + k)) * DM + fq * 128;
        uint4 kc = *(const uint4*)kp;      // 8 bf16
        #pragma unroll 1
        for (int it = 0; it < 16; ++it) {
            uint4 nx;
            if (it < 15) nx = *(const uint4*)(kp + 8);
            else         nx = kc;
            const float e0 = bflo(kc.x), e1 = bfhi(kc.x);
            const float e2 = bflo(kc.y), e3 = bfhi(kc.y);
            const float e4 = bflo(kc.z), e5 = bfhi(kc.z);
            const float e6 = bflo(kc.w), e7 = bfhi(kc.w);
            const int f0 = fq * 128 + it * 8;
            const float4 w0 = *(const float4*)&s_wv2[f0];
            const float4 w1 = *(const float4*)&s_wv2[f0 + 4];
            #pragma unroll
            for (int q = 0; q < QPB; ++q) {
                const float4 q0 = *(const float4*)&s_eq[q][f0];
                const float4 q1 = *(const float4*)&s_eq[q][f0 + 4];
                float a = acc[q];
                a = fmaf(w0.x, frcp(fmaf(e0, q0.x, 1.f)), a);
                a = fmaf(w0.y, frcp(fmaf(e1, q0.y, 1.f)), a);
                a = fmaf(w0.z, frcp(fmaf(e2, q0.z, 1.f)), a);
                a = fmaf(w0.w, frcp(fmaf(e3, q0.w, 1.f)), a);
                a = fmaf(w1.x, frcp(fmaf(e4, q1.x, 1.f)), a);
                a = fmaf(w1.y, frcp(fmaf(e5, q1.y, 1.f)), a);
                a = fmaf(w1.z, frcp(fmaf(e6, q1.z, 1.f)), a);
                a = fmaf(w1.w, frcp(fmaf(e7, q1.w, 1.f)), a);
                acc[q] = a;
            }
            kc = nx; kp += 8;
        }
    }
    #pragma unroll
    for (int q = 0; q < QPB; ++q) s_part[fq][q][k] = acc[q];
    __syncthreads();

    if (t < 64 * QPB) {   // masked softmax: wave = q-row; lane covers k, k+64
        const int q = t >> 6, ln = t & 63;
        float v0 = -3.0e38f, v1 = -3.0e38f;
        if (ln < Lv)
            v0 = s_part[0][q][ln] + s_part[1][q][ln]
               + s_part[2][q][ln] + s_part[3][q][ln];
        if (ln + 64 < Lv)
            v1 = s_part[0][q][ln+64] + s_part[1][q][ln+64]
               + s_part[2][q][ln+64] + s_part[3][q][ln+64];
        float m = fmaxf(v0, v1);
        #pragma unroll
        for (int off = 32; off; off >>= 1) m = fmaxf(m, __shfl_xor(m, off, 64));
        const float e0 = fexp2((v0 - m) * LOG2E);
        const float e1 = fexp2((v1 - m) * LOG2E);
        float s = e0 + e1;
        #pragma unroll
        for (int off = 32; off; off >>= 1) s += __shfl_xor(s, off, 64);
        const float inv = frcp(s);
        s_attn[q][ln]      = e0 * inv;
        s_attn[q][ln + 64] = e1 * inv;
    }
    __syncthreads();

    {   // PV: thread (kh = t>>8, q = (t>>6)&3, d = t&63); only k < Lv
        const int d = t & 63, q = (t >> 6) & 3, kh = t >> 8;
        const float* vb = V + ((size_t)(b * LKL + kh * 64)) * DM + h * DH + d;
        int kmax = Lv - kh * 64;
        kmax = kmax < 0 ? 0 : (kmax > 64 ? 64 : kmax);
        float a0 = 0.f, a1 = 0.f, a2 = 0.f, a3 = 0.f;
        int kk = 0;
        for (; kk + 4 <= kmax; kk += 4) {
            a0 += s_attn[q][kh*64 + kk+0] * vb[(size_t)(kk+0) * DM];
            a1 += s_attn[q][kh*64 + kk+1] * vb[(size_t)(kk+1) * DM];
            a2 += s_attn[q][kh*64 + kk+2] * vb[(size_t)(kk+2) * DM];
            a3 += s_attn[q][kh*64 + kk+3] * vb[(size_t)(kk+3) * DM];
        }
        for (; kk < kmax; ++kk) a0 += s_attn[q][kh*64 + kk] * vb[(size_t)kk * DM];
        s_pv[kh][q][d] = (a0 + a1) + (a2 + a3);
    }
    __syncthreads();
    if (t < 64 * QPB) {
        const int q = t >> 6, d = t & 63;
        interh[((size_t)(b * LQL + qbase + q)) * DM + h * DH + d] =
            (_Float16)(s_pv[0][q][d] + s_pv[1][q][d]);
    }
}

// ---- Kernel 3: out = inter @ Wo^T via MFMA (fp32 out) ----------------------
__global__ __launch_bounds__(256) void out_mfma(
    const _Float16* __restrict__ interh, const float* __restrict__ Wo,
    float* __restrict__ out)
{
    const int bm0 = blockIdx.y * 64, bn0 = blockIdx.x * 64;
    __shared__ _Float16 As[64][40];
    __shared__ _Float16 Ws[64][40];
    const int tid = threadIdx.x, wave = tid >> 6, lane = tid & 63;
    const int srow = tid >> 2, sseg = tid & 3;
    const int fr = lane & 15, fg = (lane >> 4) * 8;

    v4f acc[4] = {};
    for (int k0 = 0; k0 < DM; k0 += 32) {
        const v8h ha = *(const v8h*)(interh + (size_t)(bm0 + srow) * DM + k0 + sseg * 8);
        const float4* wp = (const float4*)(Wo + (size_t)(bn0 + srow) * DM + k0 + sseg * 8);
        const float4 w0 = wp[0], w1 = wp[1];
        __syncthreads();
        *(v8h*)&As[srow][sseg * 8] = ha;
        *(v8h*)&Ws[srow][sseg * 8] = cvt8(w0, w1);
        __syncthreads();
        const v8h af = *(const v8h*)&As[wave * 16 + fr][fg];
        #pragma unroll
        for (int sn = 0; sn < 4; ++sn) {
            const v8h bf = *(const v8h*)&Ws[sn * 16 + fr][fg];
            acc[sn] = __builtin_amdgcn_mfma_f32_16x16x32_f16(af, bf, acc[sn], 0, 0, 0);
        }
    }
    #pragma unroll
    for (int sn = 0; sn < 4; ++sn)
        #pragma unroll
        for (int rg = 0; rg < 4; ++rg) {
            const int row = bm0 + wave * 16 + (lane >> 4) * 4 + rg;
            const int col = bn0 + sn * 16 + fr;
            out[(size_t)row * DM + col] = acc[sn][rg];
        }
}

extern "C" void kernel_launch(void* const* d_in, const int* in_sizes, int n_in,
                              void* d_out, int out_size, void* d_ws, size_t ws_size,
                              hipStream_t stream)
{
    const float* xq   = (const float*)d_in[0];
    const float* xk   = (const float*)d_in[1];
    const float* xv   = (const float*)d_in[2];
    const int*   vl   = (const int*)d_in[3];
    const float* Wq   = (const float*)d_in[4];
    const float* Wk   = (const float*)d_in[5];
    const float* Wv   = (const float*)d_in[6];
    const float* Wo   = (const float*)d_in[7];
    const float* Wqa  = (const float*)d_in[8];
    const float* Wka  = (const float*)d_in[9];
    const float* wv_a = (const float*)d_in[10];
    float* out = (float*)d_out;

    // ws carve (bytes): V 512K | eqf 4M | ekf 2M | interh 256K
    char* base = (char*)d_ws;
    float*          V      = (float*)         (base);
    float*          eqf    = (float*)         (base + 524288);
    unsigned short* ekf    = (unsigned short*)(base + 4718592);
    _Float16*       interh = (_Float16*)      (base + 6815744);

    qkvfeat_mfma<<<dim3(96), dim3(256), 0, stream>>>(
        xq, xk, xv, Wq, Wk, Wv, Wqa, Wka, vl, V, eqf, ekf);
    attn_kernel<<<dim3(512), dim3(512), 0, stream>>>(
        eqf, ekf, V, wv_a, vl, interh);
    out_mfma<<<dim3(8, 4), dim3(256), 0, stream>>>(interh, Wo, out);
}

// Round 9
// 52.827 us; speedup vs baseline: 1.1707x; 1.0742x over previous
//
#include <hip/hip_runtime.h>

// Bahdanau multi-head attention, fp32 in/out, B=2 L=128 D=512 H=8 dh=64.
// R9: (a) qkvfeat phase-1 BK 32->64 (half the barriers); (b) out_mfma
//     re-tiled 32x32 -> 128 blocks (4x occupancy). attn unchanged from R8.

#define NHEADS 8
#define DH 64
#define DM 512
#define BB 2
#define LQL 128
#define LKL 128
#define QPB 4

typedef _Float16 v8h __attribute__((ext_vector_type(8)));
typedef _Float16 v4h __attribute__((ext_vector_type(4)));
typedef float v4f __attribute__((ext_vector_type(4)));

static __device__ __forceinline__ float fexp2(float x) { return __builtin_amdgcn_exp2f(x); }
static __device__ __forceinline__ float frcp(float x)  { return __builtin_amdgcn_rcpf(x); }

static __device__ __forceinline__ v8h cvt8(const float4 a, const float4 b) {
    v8h h;
    h[0] = (_Float16)a.x; h[1] = (_Float16)a.y; h[2] = (_Float16)a.z; h[3] = (_Float16)a.w;
    h[4] = (_Float16)b.x; h[5] = (_Float16)b.y; h[6] = (_Float16)b.z; h[7] = (_Float16)b.w;
    return h;
}
static __device__ __forceinline__ v4h cvt4(const float4 a) {
    v4h h;
    h[0] = (_Float16)a.x; h[1] = (_Float16)a.y;
    h[2] = (_Float16)a.z; h[3] = (_Float16)a.w;
    return h;
}

static __device__ __forceinline__ unsigned short f2bf(float x) {   // RTNE
    unsigned int u = __float_as_uint(x);
    u += 0x7FFFu + ((u >> 16) & 1u);
    return (unsigned short)(u >> 16);
}
static __device__ __forceinline__ float bflo(unsigned int u) {
    return __uint_as_float(u << 16);
}
static __device__ __forceinline__ float bfhi(unsigned int u) {
    return __uint_as_float(u & 0xFFFF0000u);
}

// ---- Kernel 1: fused QKV projection + exp'd qf/kf features ------------------
// 96 blocks x 256 thr. bid -> mat (0:Q->eqf, 1:K->ekf, 2:V), b, l-half, head.
// Phase 1: BK=64 (8 iters, 2 barriers each, 8 MFMA between barriers).
__global__ __launch_bounds__(256) void qkvfeat_mfma(
    const float* __restrict__ xq, const float* __restrict__ xk, const float* __restrict__ xv,
    const float* __restrict__ Wq, const float* __restrict__ Wk, const float* __restrict__ Wv,
    const float* __restrict__ Wqa, const float* __restrict__ Wka,
    const int* __restrict__ vl,
    float* __restrict__ V, float* __restrict__ eqf, unsigned short* __restrict__ ekf)
{
    const float C2 = 2.8853900818f;      // 2*log2(e)
    const int bid = blockIdx.x;          // 0..95
    const int mat = bid >> 5;
    const int sub = bid & 31;
    const int b  = sub >> 4;
    const int hc = (sub >> 1) & 7;       // head (mat<2) or col-tile (mat=2)
    const int lh = sub & 1;
    if (mat >= 1 && lh * 64 >= vl[b]) return;    // masked K/V row-halves

    const float* X = mat == 0 ? xq : (mat == 1 ? xk : xv);
    const float* W = mat == 0 ? Wq : (mat == 1 ? Wk : Wv);

    __shared__ _Float16 As[64][72];      // BK=64 tiles, stride 72 (2-way = free)
    __shared__ _Float16 Ws[64][72];
    __shared__ _Float16 Qt[64][72];      // phase-1 result tile (l x dh), fp16
    __shared__ _Float16 W2[64][72];      // phase-2 Wa tile (f x dh), fp16

    const int tid = threadIdx.x, wave = tid >> 6, lane = tid & 63;
    const int srow = tid >> 2, sseg16 = (tid & 3) * 16;
    const int fr = lane & 15, fg = (lane >> 4) * 8;
    const int xrow0 = b * LQL + lh * 64;
    const int wrow0 = hc * 64;

    // Phase 1: T[64x64] = X[xrow0..+64] @ W[wrow0..+64]^T, K=512, BK=64
    v4f acc[4] = {};
    for (int k0 = 0; k0 < DM; k0 += 64) {
        const float4* ap = (const float4*)(X + (size_t)(xrow0 + srow) * DM + k0 + sseg16);
        const float4 a0 = ap[0], a1 = ap[1], a2 = ap[2], a3 = ap[3];
        const float4* wp = (const float4*)(W + (size_t)(wrow0 + srow) * DM + k0 + sseg16);
        const float4 w0 = wp[0], w1 = wp[1], w2 = wp[2], w3 = wp[3];
        __syncthreads();
        *(v8h*)&As[srow][sseg16]     = cvt8(a0, a1);
        *(v8h*)&As[srow][sseg16 + 8] = cvt8(a2, a3);
        *(v8h*)&Ws[srow][sseg16]     = cvt8(w0, w1);
        *(v8h*)&Ws[srow][sseg16 + 8] = cvt8(w2, w3);
        __syncthreads();
        #pragma unroll
        for (int kk = 0; kk < 2; ++kk) {
            const v8h af = *(const v8h*)&As[wave * 16 + fr][kk * 32 + fg];
            #pragma unroll
            for (int sn = 0; sn < 4; ++sn) {
                const v8h bf = *(const v8h*)&Ws[sn * 16 + fr][kk * 32 + fg];
                acc[sn] = __builtin_amdgcn_mfma_f32_16x16x32_f16(af, bf, acc[sn], 0, 0, 0);
            }
        }
    }

    if (mat == 2) {                      // V: store fp32, done
        #pragma unroll
        for (int sn = 0; sn < 4; ++sn)
            #pragma unroll
            for (int rg = 0; rg < 4; ++rg) {
                const int row = xrow0 + wave * 16 + (lane >> 4) * 4 + rg;
                const int col = hc * 64 + sn * 16 + fr;
                V[(size_t)row * DM + col] = acc[sn][rg];
            }
        return;
    }

    // park T in LDS as fp16 (same precision path as an fp16 global roundtrip)
    #pragma unroll
    for (int sn = 0; sn < 4; ++sn)
        #pragma unroll
        for (int rg = 0; rg < 4; ++rg)
            Qt[wave * 16 + (lane >> 4) * 4 + rg][sn * 16 + fr] = (_Float16)acc[sn][rg];

    // Phase 2: F[64 x 512] = T @ Wa^T, K=64; store exp2(C2*F)
    const float* Wa = mat == 0 ? Wqa : Wka;
    const int crow0 = (b * NHEADS + hc) * LQL + lh * 64;
    const int r2 = tid >> 2, cs = (tid & 3) * 16;
    for (int ft = 0; ft < 8; ++ft) {
        const float4* wp = (const float4*)(Wa + (size_t)(ft * 64 + r2) * DH + cs);
        const float4 w0 = wp[0], w1 = wp[1], w2 = wp[2], w3 = wp[3];
        __syncthreads();                 // prev iter done reading W2 (iter0: Qt write)
        *(v8h*)&W2[r2][cs]     = cvt8(w0, w1);
        *(v8h*)&W2[r2][cs + 8] = cvt8(w2, w3);
        __syncthreads();
        v4f fa[4] = {};
        #pragma unroll
        for (int kk = 0; kk < 2; ++kk) {
            const v8h af = *(const v8h*)&Qt[wave * 16 + fr][kk * 32 + fg];
            #pragma unroll
            for (int sn = 0; sn < 4; ++sn) {
                const v8h bf = *(const v8h*)&W2[sn * 16 + fr][kk * 32 + fg];
                fa[sn] = __builtin_amdgcn_mfma_f32_16x16x32_f16(af, bf, fa[sn], 0, 0, 0);
            }
        }
        #pragma unroll
        for (int sn = 0; sn < 4; ++sn)
            #pragma unroll
            for (int rg = 0; rg < 4; ++rg) {
                const int row = crow0 + wave * 16 + (lane >> 4) * 4 + rg;
                const int col = ft * 64 + sn * 16 + fr;
                const float ev = fexp2(C2 * fa[sn][rg]);
                if (mat == 0) eqf[(size_t)row * DM + col] = ev;
                else          ekf[(size_t)row * DM + col] = f2bf(ev);
            }
    }
}

// ---- Kernel 2: fused score + masked softmax + PV — unchanged from R8 -------
__global__ __launch_bounds__(512, 2) void attn_kernel(
    const float* __restrict__ eqf, const unsigned short* __restrict__ ekf,
    const float* __restrict__ V, const float* __restrict__ wv_a,
    const int* __restrict__ vl, _Float16* __restrict__ interh)
{
    __shared__ float s_eq[QPB][DM];        // 8 KB (already exp'd)
    __shared__ float s_wv2[DM];            // 2 KB (wv * -2)
    __shared__ float s_part[4][QPB][132];
    __shared__ float s_attn[QPB][LKL];
    __shared__ float s_pv[2][QPB][DH];

    const float LOG2E = 1.4426950409f;

    const int bid = blockIdx.x;
    const int b  = bid >> 8;
    const int h  = (bid >> 5) & 7;
    const int qt = bid & 31;
    const int qbase = qt * QPB;
    const int bh = b * NHEADS + h;
    const int t = threadIdx.x;
    const int Lv = vl[b];

    {   // stage eqf (direct copy) and wv (pre-scaled by -2)
        const int r = t >> 7, cc = (t & 127) * 4;
        *(float4*)&s_eq[r][cc] =
            *(const float4*)(eqf + ((size_t)(bh * LQL + qbase + r)) * DM + cc);
        s_wv2[t] = wv_a[t] * -2.0f;
    }
    __syncthreads();

    const int w = t >> 6, lane = t & 63;
    const int k  = w * 16 + (lane & 15);   // wave covers 16 consecutive k
    const int fq = lane >> 4;
    float acc[QPB] = {};
    if (k < Lv) {
        const unsigned short* kp = ekf + ((size_t)(bh * LKL + k)) * DM + fq * 128;
        uint4 kc = *(const uint4*)kp;      // 8 bf16
        #pragma unroll 1
        for (int it = 0; it < 16; ++it) {
            uint4 nx;
            if (it < 15) nx = *(const uint4*)(kp + 8);
            else         nx = kc;
            const float e0 = bflo(kc.x), e1 = bfhi(kc.x);
            const float e2 = bflo(kc.y), e3 = bfhi(kc.y);
            const float e4 = bflo(kc.z), e5 = bfhi(kc.z);
            const float e6 = bflo(kc.w), e7 = bfhi(kc.w);
            const int f0 = fq * 128 + it * 8;
            const float4 w0 = *(const float4*)&s_wv2[f0];
            const float4 w1 = *(const float4*)&s_wv2[f0 + 4];
            #pragma unroll
            for (int q = 0; q < QPB; ++q) {
                const float4 q0 = *(const float4*)&s_eq[q][f0];
                const float4 q1 = *(const float4*)&s_eq[q][f0 + 4];
                float a = acc[q];
                a = fmaf(w0.x, frcp(fmaf(e0, q0.x, 1.f)), a);
                a = fmaf(w0.y, frcp(fmaf(e1, q0.y, 1.f)), a);
                a = fmaf(w0.z, frcp(fmaf(e2, q0.z, 1.f)), a);
                a = fmaf(w0.w, frcp(fmaf(e3, q0.w, 1.f)), a);
                a = fmaf(w1.x, frcp(fmaf(e4, q1.x, 1.f)), a);
                a = fmaf(w1.y, frcp(fmaf(e5, q1.y, 1.f)), a);
                a = fmaf(w1.z, frcp(fmaf(e6, q1.z, 1.f)), a);
                a = fmaf(w1.w, frcp(fmaf(e7, q1.w, 1.f)), a);
                acc[q] = a;
            }
            kc = nx; kp += 8;
        }
    }
    #pragma unroll
    for (int q = 0; q < QPB; ++q) s_part[fq][q][k] = acc[q];
    __syncthreads();

    if (t < 64 * QPB) {   // masked softmax: wave = q-row; lane covers k, k+64
        const int q = t >> 6, ln = t & 63;
        float v0 = -3.0e38f, v1 = -3.0e38f;
        if (ln < Lv)
            v0 = s_part[0][q][ln] + s_part[1][q][ln]
               + s_part[2][q][ln] + s_part[3][q][ln];
        if (ln + 64 < Lv)
            v1 = s_part[0][q][ln+64] + s_part[1][q][ln+64]
               + s_part[2][q][ln+64] + s_part[3][q][ln+64];
        float m = fmaxf(v0, v1);
        #pragma unroll
        for (int off = 32; off; off >>= 1) m = fmaxf(m, __shfl_xor(m, off, 64));
        const float e0 = fexp2((v0 - m) * LOG2E);
        const float e1 = fexp2((v1 - m) * LOG2E);
        float s = e0 + e1;
        #pragma unroll
        for (int off = 32; off; off >>= 1) s += __shfl_xor(s, off, 64);
        const float inv = frcp(s);
        s_attn[q][ln]      = e0 * inv;
        s_attn[q][ln + 64] = e1 * inv;
    }
    __syncthreads();

    {   // PV: thread (kh = t>>8, q = (t>>6)&3, d = t&63); only k < Lv
        const int d = t & 63, q = (t >> 6) & 3, kh = t >> 8;
        const float* vb = V + ((size_t)(b * LKL + kh * 64)) * DM + h * DH + d;
        int kmax = Lv - kh * 64;
        kmax = kmax < 0 ? 0 : (kmax > 64 ? 64 : kmax);
        float a0 = 0.f, a1 = 0.f, a2 = 0.f, a3 = 0.f;
        int kk = 0;
        for (; kk + 4 <= kmax; kk += 4) {
            a0 += s_attn[q][kh*64 + kk+0] * vb[(size_t)(kk+0) * DM];
            a1 += s_attn[q][kh*64 + kk+1] * vb[(size_t)(kk+1) * DM];
            a2 += s_attn[q][kh*64 + kk+2] * vb[(size_t)(kk+2) * DM];
            a3 += s_attn[q][kh*64 + kk+3] * vb[(size_t)(kk+3) * DM];
        }
        for (; kk < kmax; ++kk) a0 += s_attn[q][kh*64 + kk] * vb[(size_t)kk * DM];
        s_pv[kh][q][d] = (a0 + a1) + (a2 + a3);
    }
    __syncthreads();
    if (t < 64 * QPB) {
        const int q = t >> 6, d = t & 63;
        interh[((size_t)(b * LQL + qbase + q)) * DM + h * DH + d] =
            (_Float16)(s_pv[0][q][d] + s_pv[1][q][d]);
    }
}

// ---- Kernel 3: out = inter @ Wo^T, 32x32 tiles x 128 blocks ----------------
__global__ __launch_bounds__(256) void out_mfma(
    const _Float16* __restrict__ interh, const float* __restrict__ Wo,
    float* __restrict__ out)
{
    const int bm0 = blockIdx.y * 32, bn0 = blockIdx.x * 32;
    __shared__ _Float16 As[32][40];
    __shared__ _Float16 Ws[32][40];
    const int tid = threadIdx.x, wave = tid >> 6, lane = tid & 63;
    const int ms = wave & 1, ns = wave >> 1;       // 2x2 of 16x16 fragments
    const int srow = tid >> 3, sseg = tid & 7;     // 32 rows x 8 segs of 4
    const int fr = lane & 15, fg = (lane >> 4) * 8;

    v4f acc = {};
    for (int k0 = 0; k0 < DM; k0 += 32) {
        const v4h ha = *(const v4h*)(interh + (size_t)(bm0 + srow) * DM + k0 + sseg * 4);
        const float4 w4 = *(const float4*)(Wo + (size_t)(bn0 + srow) * DM + k0 + sseg * 4);
        __syncthreads();
        *(v4h*)&As[srow][sseg * 4] = ha;
        *(v4h*)&Ws[srow][sseg * 4] = cvt4(w4);
        __syncthreads();
        const v8h af = *(const v8h*)&As[ms * 16 + fr][fg];
        const v8h bf = *(const v8h*)&Ws[ns * 16 + fr][fg];
        acc = __builtin_amdgcn_mfma_f32_16x16x32_f16(af, bf, acc, 0, 0, 0);
    }
    #pragma unroll
    for (int rg = 0; rg < 4; ++rg) {
        const int row = bm0 + ms * 16 + (lane >> 4) * 4 + rg;
        const int col = bn0 + ns * 16 + fr;
        out[(size_t)row * DM + col] = acc[rg];
    }
}

extern "C" void kernel_launch(void* const* d_in, const int* in_sizes, int n_in,
                              void* d_out, int out_size, void* d_ws, size_t ws_size,
                              hipStream_t stream)
{
    const float* xq   = (const float*)d_in[0];
    const float* xk   = (const float*)d_in[1];
    const float* xv   = (const float*)d_in[2];
    const int*   vl   = (const int*)d_in[3];
    const float* Wq   = (const float*)d_in[4];
    const float* Wk   = (const float*)d_in[5];
    const float* Wv   = (const float*)d_in[6];
    const float* Wo   = (const float*)d_in[7];
    const float* Wqa  = (const float*)d_in[8];
    const float* Wka  = (const float*)d_in[9];
    const float* wv_a = (const float*)d_in[10];
    float* out = (float*)d_out;

    // ws carve (bytes): V 512K | eqf 4M | ekf 2M | interh 256K
    char* base = (char*)d_ws;
    float*          V      = (float*)         (base);
    float*          eqf    = (float*)         (base + 524288);
    unsigned short* ekf    = (unsigned short*)(base + 4718592);
    _Float16*       interh = (_Float16*)      (base + 6815744);

    qkvfeat_mfma<<<dim3(96), dim3(256), 0, stream>>>(
        xq, xk, xv, Wq, Wk, Wv, Wqa, Wka, vl, V, eqf, ekf);
    attn_kernel<<<dim3(512), dim3(512), 0, stream>>>(
        eqf, ekf, V, wv_a, vl, interh);
    out_mfma<<<dim3(16, 8), dim3(256), 0, stream>>>(interh, Wo, out);
}

// Round 10
// 44.773 us; speedup vs baseline: 1.3813x; 1.1799x over previous
//
#include <hip/hip_runtime.h>

// Bahdanau multi-head attention, fp32 in/out, B=2 L=128 D=512 H=8 dh=64.
// R10: (a) qkvfeat split into feature-halves: 160 blocks (was 96), phase-2
//      halved per block; (b) attn: in-wave shfl_xor fq-reduction replaces
//      s_part LDS roundtrip; (c) attn XCD-chunked block swizzle.

#define NHEADS 8
#define DH 64
#define DM 512
#define BB 2
#define LQL 128
#define LKL 128
#define QPB 4

typedef _Float16 v8h __attribute__((ext_vector_type(8)));
typedef _Float16 v4h __attribute__((ext_vector_type(4)));
typedef float v4f __attribute__((ext_vector_type(4)));

static __device__ __forceinline__ float fexp2(float x) { return __builtin_amdgcn_exp2f(x); }
static __device__ __forceinline__ float frcp(float x)  { return __builtin_amdgcn_rcpf(x); }

static __device__ __forceinline__ v8h cvt8(const float4 a, const float4 b) {
    v8h h;
    h[0] = (_Float16)a.x; h[1] = (_Float16)a.y; h[2] = (_Float16)a.z; h[3] = (_Float16)a.w;
    h[4] = (_Float16)b.x; h[5] = (_Float16)b.y; h[6] = (_Float16)b.z; h[7] = (_Float16)b.w;
    return h;
}
static __device__ __forceinline__ v4h cvt4(const float4 a) {
    v4h h;
    h[0] = (_Float16)a.x; h[1] = (_Float16)a.y;
    h[2] = (_Float16)a.z; h[3] = (_Float16)a.w;
    return h;
}

static __device__ __forceinline__ unsigned short f2bf(float x) {   // RTNE
    unsigned int u = __float_as_uint(x);
    u += 0x7FFFu + ((u >> 16) & 1u);
    return (unsigned short)(u >> 16);
}
static __device__ __forceinline__ float bflo(unsigned int u) {
    return __uint_as_float(u << 16);
}
static __device__ __forceinline__ float bfhi(unsigned int u) {
    return __uint_as_float(u & 0xFFFF0000u);
}

// ---- Kernel 1: fused QKV projection + exp'd qf/kf features ------------------
// 160 blocks x 256 thr. bid<128: (mat Q/K, b, head, l-half, f-half); phase 1
// recomputed per f-half (cheap), phase 2 covers 4 of 8 ft tiles.
// bid>=128: V projection tile, phase 1 only.
__global__ __launch_bounds__(256) void qkvfeat_mfma(
    const float* __restrict__ xq, const float* __restrict__ xk, const float* __restrict__ xv,
    const float* __restrict__ Wq, const float* __restrict__ Wk, const float* __restrict__ Wv,
    const float* __restrict__ Wqa, const float* __restrict__ Wka,
    const int* __restrict__ vl,
    float* __restrict__ V, float* __restrict__ eqf, unsigned short* __restrict__ ekf)
{
    const float C2 = 2.8853900818f;      // 2*log2(e)
    const int bid = blockIdx.x;          // 0..159
    int mat, b, hc, lh, fh;
    if (bid < 128) {
        mat = bid >> 6;                  // 0:Q->eqf, 1:K->ekf
        const int sub = bid & 63;
        b  = sub >> 5;
        hc = (sub >> 2) & 7;
        lh = (sub >> 1) & 1;
        fh = sub & 1;                    // feature half for phase 2
    } else {
        mat = 2;                         // V
        const int sub = bid - 128;
        b  = sub >> 4;
        hc = (sub >> 1) & 7;             // col-tile
        lh = sub & 1;
        fh = 0;
    }
    if (mat >= 1 && lh * 64 >= vl[b]) return;    // masked K/V row-halves

    const float* X = mat == 0 ? xq : (mat == 1 ? xk : xv);
    const float* W = mat == 0 ? Wq : (mat == 1 ? Wk : Wv);

    __shared__ _Float16 As[64][72];      // BK=64 tiles, stride 72 (2-way = free)
    __shared__ _Float16 Ws[64][72];
    __shared__ _Float16 Qt[64][72];      // phase-1 result tile (l x dh), fp16
    __shared__ _Float16 W2[64][72];      // phase-2 Wa tile (f x dh), fp16

    const int tid = threadIdx.x, wave = tid >> 6, lane = tid & 63;
    const int srow = tid >> 2, sseg16 = (tid & 3) * 16;
    const int fr = lane & 15, fg = (lane >> 4) * 8;
    const int xrow0 = b * LQL + lh * 64;
    const int wrow0 = hc * 64;

    // Phase 1: T[64x64] = X[xrow0..+64] @ W[wrow0..+64]^T, K=512, BK=64
    v4f acc[4] = {};
    for (int k0 = 0; k0 < DM; k0 += 64) {
        const float4* ap = (const float4*)(X + (size_t)(xrow0 + srow) * DM + k0 + sseg16);
        const float4 a0 = ap[0], a1 = ap[1], a2 = ap[2], a3 = ap[3];
        const float4* wp = (const float4*)(W + (size_t)(wrow0 + srow) * DM + k0 + sseg16);
        const float4 w0 = wp[0], w1 = wp[1], w2 = wp[2], w3 = wp[3];
        __syncthreads();
        *(v8h*)&As[srow][sseg16]     = cvt8(a0, a1);
        *(v8h*)&As[srow][sseg16 + 8] = cvt8(a2, a3);
        *(v8h*)&Ws[srow][sseg16]     = cvt8(w0, w1);
        *(v8h*)&Ws[srow][sseg16 + 8] = cvt8(w2, w3);
        __syncthreads();
        #pragma unroll
        for (int kk = 0; kk < 2; ++kk) {
            const v8h af = *(const v8h*)&As[wave * 16 + fr][kk * 32 + fg];
            #pragma unroll
            for (int sn = 0; sn < 4; ++sn) {
                const v8h bf = *(const v8h*)&Ws[sn * 16 + fr][kk * 32 + fg];
                acc[sn] = __builtin_amdgcn_mfma_f32_16x16x32_f16(af, bf, acc[sn], 0, 0, 0);
            }
        }
    }

    if (mat == 2) {                      // V: store fp32, done
        #pragma unroll
        for (int sn = 0; sn < 4; ++sn)
            #pragma unroll
            for (int rg = 0; rg < 4; ++rg) {
                const int row = xrow0 + wave * 16 + (lane >> 4) * 4 + rg;
                const int col = hc * 64 + sn * 16 + fr;
                V[(size_t)row * DM + col] = acc[sn][rg];
            }
        return;
    }

    // park T in LDS as fp16 (same precision path as an fp16 global roundtrip)
    #pragma unroll
    for (int sn = 0; sn < 4; ++sn)
        #pragma unroll
        for (int rg = 0; rg < 4; ++rg)
            Qt[wave * 16 + (lane >> 4) * 4 + rg][sn * 16 + fr] = (_Float16)acc[sn][rg];

    // Phase 2: F[64 x 256] = T @ Wa[fh half]^T, K=64; store exp2(C2*F)
    const float* Wa = mat == 0 ? Wqa : Wka;
    const int crow0 = (b * NHEADS + hc) * LQL + lh * 64;
    const int r2 = tid >> 2, cs = (tid & 3) * 16;
    for (int ft = fh * 4; ft < fh * 4 + 4; ++ft) {
        const float4* wp = (const float4*)(Wa + (size_t)(ft * 64 + r2) * DH + cs);
        const float4 w0 = wp[0], w1 = wp[1], w2 = wp[2], w3 = wp[3];
        __syncthreads();                 // prev iter done reading W2 (iter0: Qt write)
        *(v8h*)&W2[r2][cs]     = cvt8(w0, w1);
        *(v8h*)&W2[r2][cs + 8] = cvt8(w2, w3);
        __syncthreads();
        v4f fa[4] = {};
        #pragma unroll
        for (int kk = 0; kk < 2; ++kk) {
            const v8h af = *(const v8h*)&Qt[wave * 16 + fr][kk * 32 + fg];
            #pragma unroll
            for (int sn = 0; sn < 4; ++sn) {
                const v8h bf = *(const v8h*)&W2[sn * 16 + fr][kk * 32 + fg];
                fa[sn] = __builtin_amdgcn_mfma_f32_16x16x32_f16(af, bf, fa[sn], 0, 0, 0);
            }
        }
        #pragma unroll
        for (int sn = 0; sn < 4; ++sn)
            #pragma unroll
            for (int rg = 0; rg < 4; ++rg) {
                const int row = crow0 + wave * 16 + (lane >> 4) * 4 + rg;
                const int col = ft * 64 + sn * 16 + fr;
                const float ev = fexp2(C2 * fa[sn][rg]);
                if (mat == 0) eqf[(size_t)row * DM + col] = ev;
                else          ekf[(size_t)row * DM + col] = f2bf(ev);
            }
    }
}

// ---- Kernel 2: fused score + masked softmax + PV ----------------------------
// 512 blocks (XCD-chunk-swizzled), 512 thr. Wave w owns k in [w*16,w*16+16),
// lane = (k&15)|(fq<<4). fq partials reduced in-wave via shfl_xor(16/32).
__global__ __launch_bounds__(512, 2) void attn_kernel(
    const float* __restrict__ eqf, const unsigned short* __restrict__ ekf,
    const float* __restrict__ V, const float* __restrict__ wv_a,
    const int* __restrict__ vl, _Float16* __restrict__ interh)
{
    __shared__ float s_eq[QPB][DM];        // 8 KB (already exp'd)
    __shared__ float s_wv2[DM];            // 2 KB (wv * -2)
    __shared__ float s_score[QPB][132];    // reduced scores (2.1 KB)
    __shared__ float s_attn[QPB][LKL];
    __shared__ float s_pv[2][QPB][DH];

    const float LOG2E = 1.4426950409f;

    // XCD-chunked swizzle: 64 consecutive qtile-blocks (one (b,h) slab) per XCD
    const int bid = (blockIdx.x & 7) * 64 + (blockIdx.x >> 3);
    const int b  = bid >> 8;
    const int h  = (bid >> 5) & 7;
    const int qt = bid & 31;
    const int qbase = qt * QPB;
    const int bh = b * NHEADS + h;
    const int t = threadIdx.x;
    const int Lv = vl[b];

    {   // stage eqf (direct copy) and wv (pre-scaled by -2)
        const int r = t >> 7, cc = (t & 127) * 4;
        *(float4*)&s_eq[r][cc] =
            *(const float4*)(eqf + ((size_t)(bh * LQL + qbase + r)) * DM + cc);
        s_wv2[t] = wv_a[t] * -2.0f;
    }
    __syncthreads();

    const int w = t >> 6, lane = t & 63;
    const int k  = w * 16 + (lane & 15);   // wave covers 16 consecutive k
    const int fq = lane >> 4;
    float acc[QPB] = {};
    if (k < Lv) {
        const unsigned short* kp = ekf + ((size_t)(bh * LKL + k)) * DM + fq * 128;
        uint4 kc = *(const uint4*)kp;      // 8 bf16
        #pragma unroll 1
        for (int it = 0; it < 16; ++it) {
            uint4 nx;
            if (it < 15) nx = *(const uint4*)(kp + 8);
            else         nx = kc;
            const float e0 = bflo(kc.x), e1 = bfhi(kc.x);
            const float e2 = bflo(kc.y), e3 = bfhi(kc.y);
            const float e4 = bflo(kc.z), e5 = bfhi(kc.z);
            const float e6 = bflo(kc.w), e7 = bfhi(kc.w);
            const int f0 = fq * 128 + it * 8;
            const float4 w0 = *(const float4*)&s_wv2[f0];
            const float4 w1 = *(const float4*)&s_wv2[f0 + 4];
            #pragma unroll
            for (int q = 0; q < QPB; ++q) {
                const float4 q0 = *(const float4*)&s_eq[q][f0];
                const float4 q1 = *(const float4*)&s_eq[q][f0 + 4];
                float a = acc[q];
                a = fmaf(w0.x, frcp(fmaf(e0, q0.x, 1.f)), a);
                a = fmaf(w0.y, frcp(fmaf(e1, q0.y, 1.f)), a);
                a = fmaf(w0.z, frcp(fmaf(e2, q0.z, 1.f)), a);
                a = fmaf(w0.w, frcp(fmaf(e3, q0.w, 1.f)), a);
                a = fmaf(w1.x, frcp(fmaf(e4, q1.x, 1.f)), a);
                a = fmaf(w1.y, frcp(fmaf(e5, q1.y, 1.f)), a);
                a = fmaf(w1.z, frcp(fmaf(e6, q1.z, 1.f)), a);
                a = fmaf(w1.w, frcp(fmaf(e7, q1.w, 1.f)), a);
                acc[q] = a;
            }
            kc = nx; kp += 8;
        }
    }
    // in-wave 4-way fq reduction: partials for k live in lanes {k,k+16,k+32,k+48}
    #pragma unroll
    for (int q = 0; q < QPB; ++q) {
        float a = acc[q];
        a += __shfl_xor(a, 16, 64);
        a += __shfl_xor(a, 32, 64);
        if (lane < 16) s_score[q][k] = a;
    }
    __syncthreads();

    if (t < 64 * QPB) {   // masked softmax: wave = q-row; lane covers k, k+64
        const int q = t >> 6, ln = t & 63;
        const float v0 = (ln < Lv)      ? s_score[q][ln]      : -3.0e38f;
        const float v1 = (ln + 64 < Lv) ? s_score[q][ln + 64] : -3.0e38f;
        float m = fmaxf(v0, v1);
        #pragma unroll
        for (int off = 32; off; off >>= 1) m = fmaxf(m, __shfl_xor(m, off, 64));
        const float e0 = fexp2((v0 - m) * LOG2E);
        const float e1 = fexp2((v1 - m) * LOG2E);
        float s = e0 + e1;
        #pragma unroll
        for (int off = 32; off; off >>= 1) s += __shfl_xor(s, off, 64);
        const float inv = frcp(s);
        s_attn[q][ln]      = e0 * inv;
        s_attn[q][ln + 64] = e1 * inv;
    }
    __syncthreads();

    {   // PV: thread (kh = t>>8, q = (t>>6)&3, d = t&63); only k < Lv
        const int d = t & 63, q = (t >> 6) & 3, kh = t >> 8;
        const float* vb = V + ((size_t)(b * LKL + kh * 64)) * DM + h * DH + d;
        int kmax = Lv - kh * 64;
        kmax = kmax < 0 ? 0 : (kmax > 64 ? 64 : kmax);
        float a0 = 0.f, a1 = 0.f, a2 = 0.f, a3 = 0.f;
        int kk = 0;
        for (; kk + 4 <= kmax; kk += 4) {
            a0 += s_attn[q][kh*64 + kk+0] * vb[(size_t)(kk+0) * DM];
            a1 += s_attn[q][kh*64 + kk+1] * vb[(size_t)(kk+1) * DM];
            a2 += s_attn[q][kh*64 + kk+2] * vb[(size_t)(kk+2) * DM];
            a3 += s_attn[q][kh*64 + kk+3] * vb[(size_t)(kk+3) * DM];
        }
        for (; kk < kmax; ++kk) a0 += s_attn[q][kh*64 + kk] * vb[(size_t)kk * DM];
        s_pv[kh][q][d] = (a0 + a1) + (a2 + a3);
    }
    __syncthreads();
    if (t < 64 * QPB) {
        const int q = t >> 6, d = t & 63;
        interh[((size_t)(b * LQL + qbase + q)) * DM + h * DH + d] =
            (_Float16)(s_pv[0][q][d] + s_pv[1][q][d]);
    }
}

// ---- Kernel 3: out = inter @ Wo^T, 32x32 tiles x 128 blocks ----------------
__global__ __launch_bounds__(256) void out_mfma(
    const _Float16* __restrict__ interh, const float* __restrict__ Wo,
    float* __restrict__ out)
{
    const int bm0 = blockIdx.y * 32, bn0 = blockIdx.x * 32;
    __shared__ _Float16 As[32][40];
    __shared__ _Float16 Ws[32][40];
    const int tid = threadIdx.x, wave = tid >> 6, lane = tid & 63;
    const int ms = wave & 1, ns = wave >> 1;       // 2x2 of 16x16 fragments
    const int srow = tid >> 3, sseg = tid & 7;     // 32 rows x 8 segs of 4
    const int fr = lane & 15, fg = (lane >> 4) * 8;

    v4f acc = {};
    for (int k0 = 0; k0 < DM; k0 += 32) {
        const v4h ha = *(const v4h*)(interh + (size_t)(bm0 + srow) * DM + k0 + sseg * 4);
        const float4 w4 = *(const float4*)(Wo + (size_t)(bn0 + srow) * DM + k0 + sseg * 4);
        __syncthreads();
        *(v4h*)&As[srow][sseg * 4] = ha;
        *(v4h*)&Ws[srow][sseg * 4] = cvt4(w4);
        __syncthreads();
        const v8h af = *(const v8h*)&As[ms * 16 + fr][fg];
        const v8h bf = *(const v8h*)&Ws[ns * 16 + fr][fg];
        acc = __builtin_amdgcn_mfma_f32_16x16x32_f16(af, bf, acc, 0, 0, 0);
    }
    #pragma unroll
    for (int rg = 0; rg < 4; ++rg) {
        const int row = bm0 + ms * 16 + (lane >> 4) * 4 + rg;
        const int col = bn0 + ns * 16 + fr;
        out[(size_t)row * DM + col] = acc[rg];
    }
}

extern "C" void kernel_launch(void* const* d_in, const int* in_sizes, int n_in,
                              void* d_out, int out_size, void* d_ws, size_t ws_size,
                              hipStream_t stream)
{
    const float* xq   = (const float*)d_in[0];
    const float* xk   = (const float*)d_in[1];
    const float* xv   = (const float*)d_in[2];
    const int*   vl   = (const int*)d_in[3];
    const float* Wq   = (const float*)d_in[4];
    const float* Wk   = (const float*)d_in[5];
    const float* Wv   = (const float*)d_in[6];
    const float* Wo   = (const float*)d_in[7];
    const float* Wqa  = (const float*)d_in[8];
    const float* Wka  = (const float*)d_in[9];
    const float* wv_a = (const float*)d_in[10];
    float* out = (float*)d_out;

    // ws carve (bytes): V 512K | eqf 4M | ekf 2M | interh 256K
    char* base = (char*)d_ws;
    float*          V      = (float*)         (base);
    float*          eqf    = (float*)         (base + 524288);
    unsigned short* ekf    = (unsigned short*)(base + 4718592);
    _Float16*       interh = (_Float16*)      (base + 6815744);

    qkvfeat_mfma<<<dim3(160), dim3(256), 0, stream>>>(
        xq, xk, xv, Wq, Wk, Wv, Wqa, Wka, vl, V, eqf, ekf);
    attn_kernel<<<dim3(512), dim3(512), 0, stream>>>(
        eqf, ekf, V, wv_a, vl, interh);
    out_mfma<<<dim3(16, 8), dim3(256), 0, stream>>>(interh, Wo, out);
}

// Round 11
// 44.202 us; speedup vs baseline: 1.3992x; 1.0129x over previous
//
#include <hip/hip_runtime.h>

// Bahdanau multi-head attention, fp32 in/out, B=2 L=128 D=512 H=8 dh=64.
// R11: attn score loop uses paired-rcp: w0/pa + w1/pb = (w0*pb+w1*pa)*rcp(pa*pb)
//      -> 1 trans per 2 evals (was 1 per eval). Everything else = R10.

#define NHEADS 8
#define DH 64
#define DM 512
#define BB 2
#define LQL 128
#define LKL 128
#define QPB 4

typedef _Float16 v8h __attribute__((ext_vector_type(8)));
typedef _Float16 v4h __attribute__((ext_vector_type(4)));
typedef float v4f __attribute__((ext_vector_type(4)));

static __device__ __forceinline__ float fexp2(float x) { return __builtin_amdgcn_exp2f(x); }
static __device__ __forceinline__ float frcp(float x)  { return __builtin_amdgcn_rcpf(x); }

static __device__ __forceinline__ v8h cvt8(const float4 a, const float4 b) {
    v8h h;
    h[0] = (_Float16)a.x; h[1] = (_Float16)a.y; h[2] = (_Float16)a.z; h[3] = (_Float16)a.w;
    h[4] = (_Float16)b.x; h[5] = (_Float16)b.y; h[6] = (_Float16)b.z; h[7] = (_Float16)b.w;
    return h;
}
static __device__ __forceinline__ v4h cvt4(const float4 a) {
    v4h h;
    h[0] = (_Float16)a.x; h[1] = (_Float16)a.y;
    h[2] = (_Float16)a.z; h[3] = (_Float16)a.w;
    return h;
}

static __device__ __forceinline__ unsigned short f2bf(float x) {   // RTNE
    unsigned int u = __float_as_uint(x);
    u += 0x7FFFu + ((u >> 16) & 1u);
    return (unsigned short)(u >> 16);
}
static __device__ __forceinline__ float bflo(unsigned int u) {
    return __uint_as_float(u << 16);
}
static __device__ __forceinline__ float bfhi(unsigned int u) {
    return __uint_as_float(u & 0xFFFF0000u);
}

// ---- Kernel 1: fused QKV projection + exp'd qf/kf features ------------------
// 160 blocks x 256 thr. bid<128: (mat Q/K, b, head, l-half, f-half); phase 1
// recomputed per f-half (cheap), phase 2 covers 4 of 8 ft tiles.
// bid>=128: V projection tile, phase 1 only.
__global__ __launch_bounds__(256) void qkvfeat_mfma(
    const float* __restrict__ xq, const float* __restrict__ xk, const float* __restrict__ xv,
    const float* __restrict__ Wq, const float* __restrict__ Wk, const float* __restrict__ Wv,
    const float* __restrict__ Wqa, const float* __restrict__ Wka,
    const int* __restrict__ vl,
    float* __restrict__ V, float* __restrict__ eqf, unsigned short* __restrict__ ekf)
{
    const float C2 = 2.8853900818f;      // 2*log2(e)
    const int bid = blockIdx.x;          // 0..159
    int mat, b, hc, lh, fh;
    if (bid < 128) {
        mat = bid >> 6;                  // 0:Q->eqf, 1:K->ekf
        const int sub = bid & 63;
        b  = sub >> 5;
        hc = (sub >> 2) & 7;
        lh = (sub >> 1) & 1;
        fh = sub & 1;                    // feature half for phase 2
    } else {
        mat = 2;                         // V
        const int sub = bid - 128;
        b  = sub >> 4;
        hc = (sub >> 1) & 7;             // col-tile
        lh = sub & 1;
        fh = 0;
    }
    if (mat >= 1 && lh * 64 >= vl[b]) return;    // masked K/V row-halves

    const float* X = mat == 0 ? xq : (mat == 1 ? xk : xv);
    const float* W = mat == 0 ? Wq : (mat == 1 ? Wk : Wv);

    __shared__ _Float16 As[64][72];      // BK=64 tiles, stride 72 (2-way = free)
    __shared__ _Float16 Ws[64][72];
    __shared__ _Float16 Qt[64][72];      // phase-1 result tile (l x dh), fp16
    __shared__ _Float16 W2[64][72];      // phase-2 Wa tile (f x dh), fp16

    const int tid = threadIdx.x, wave = tid >> 6, lane = tid & 63;
    const int srow = tid >> 2, sseg16 = (tid & 3) * 16;
    const int fr = lane & 15, fg = (lane >> 4) * 8;
    const int xrow0 = b * LQL + lh * 64;
    const int wrow0 = hc * 64;

    // Phase 1: T[64x64] = X[xrow0..+64] @ W[wrow0..+64]^T, K=512, BK=64
    v4f acc[4] = {};
    for (int k0 = 0; k0 < DM; k0 += 64) {
        const float4* ap = (const float4*)(X + (size_t)(xrow0 + srow) * DM + k0 + sseg16);
        const float4 a0 = ap[0], a1 = ap[1], a2 = ap[2], a3 = ap[3];
        const float4* wp = (const float4*)(W + (size_t)(wrow0 + srow) * DM + k0 + sseg16);
        const float4 w0 = wp[0], w1 = wp[1], w2 = wp[2], w3 = wp[3];
        __syncthreads();
        *(v8h*)&As[srow][sseg16]     = cvt8(a0, a1);
        *(v8h*)&As[srow][sseg16 + 8] = cvt8(a2, a3);
        *(v8h*)&Ws[srow][sseg16]     = cvt8(w0, w1);
        *(v8h*)&Ws[srow][sseg16 + 8] = cvt8(w2, w3);
        __syncthreads();
        #pragma unroll
        for (int kk = 0; kk < 2; ++kk) {
            const v8h af = *(const v8h*)&As[wave * 16 + fr][kk * 32 + fg];
            #pragma unroll
            for (int sn = 0; sn < 4; ++sn) {
                const v8h bf = *(const v8h*)&Ws[sn * 16 + fr][kk * 32 + fg];
                acc[sn] = __builtin_amdgcn_mfma_f32_16x16x32_f16(af, bf, acc[sn], 0, 0, 0);
            }
        }
    }

    if (mat == 2) {                      // V: store fp32, done
        #pragma unroll
        for (int sn = 0; sn < 4; ++sn)
            #pragma unroll
            for (int rg = 0; rg < 4; ++rg) {
                const int row = xrow0 + wave * 16 + (lane >> 4) * 4 + rg;
                const int col = hc * 64 + sn * 16 + fr;
                V[(size_t)row * DM + col] = acc[sn][rg];
            }
        return;
    }

    // park T in LDS as fp16 (same precision path as an fp16 global roundtrip)
    #pragma unroll
    for (int sn = 0; sn < 4; ++sn)
        #pragma unroll
        for (int rg = 0; rg < 4; ++rg)
            Qt[wave * 16 + (lane >> 4) * 4 + rg][sn * 16 + fr] = (_Float16)acc[sn][rg];

    // Phase 2: F[64 x 256] = T @ Wa[fh half]^T, K=64; store exp2(C2*F)
    const float* Wa = mat == 0 ? Wqa : Wka;
    const int crow0 = (b * NHEADS + hc) * LQL + lh * 64;
    const int r2 = tid >> 2, cs = (tid & 3) * 16;
    for (int ft = fh * 4; ft < fh * 4 + 4; ++ft) {
        const float4* wp = (const float4*)(Wa + (size_t)(ft * 64 + r2) * DH + cs);
        const float4 w0 = wp[0], w1 = wp[1], w2 = wp[2], w3 = wp[3];
        __syncthreads();                 // prev iter done reading W2 (iter0: Qt write)
        *(v8h*)&W2[r2][cs]     = cvt8(w0, w1);
        *(v8h*)&W2[r2][cs + 8] = cvt8(w2, w3);
        __syncthreads();
        v4f fa[4] = {};
        #pragma unroll
        for (int kk = 0; kk < 2; ++kk) {
            const v8h af = *(const v8h*)&Qt[wave * 16 + fr][kk * 32 + fg];
            #pragma unroll
            for (int sn = 0; sn < 4; ++sn) {
                const v8h bf = *(const v8h*)&W2[sn * 16 + fr][kk * 32 + fg];
                fa[sn] = __builtin_amdgcn_mfma_f32_16x16x32_f16(af, bf, fa[sn], 0, 0, 0);
            }
        }
        #pragma unroll
        for (int sn = 0; sn < 4; ++sn)
            #pragma unroll
            for (int rg = 0; rg < 4; ++rg) {
                const int row = crow0 + wave * 16 + (lane >> 4) * 4 + rg;
                const int col = ft * 64 + sn * 16 + fr;
                const float ev = fexp2(C2 * fa[sn][rg]);
                if (mat == 0) eqf[(size_t)row * DM + col] = ev;
                else          ekf[(size_t)row * DM + col] = f2bf(ev);
            }
    }
}

// ---- Kernel 2: fused score + masked softmax + PV ----------------------------
// 512 blocks (XCD-chunk-swizzled), 512 thr. Wave w owns k in [w*16,w*16+16),
// lane = (k&15)|(fq<<4). Score pairs share one rcp:
//   w0/pa + w1/pb = (w0*pb + w1*pa) * rcp(pa*pb).
__global__ __launch_bounds__(512, 2) void attn_kernel(
    const float* __restrict__ eqf, const unsigned short* __restrict__ ekf,
    const float* __restrict__ V, const float* __restrict__ wv_a,
    const int* __restrict__ vl, _Float16* __restrict__ interh)
{
    __shared__ float s_eq[QPB][DM];        // 8 KB (already exp'd)
    __shared__ float s_wv2[DM];            // 2 KB (wv * -2)
    __shared__ float s_score[QPB][132];    // reduced scores (2.1 KB)
    __shared__ float s_attn[QPB][LKL];
    __shared__ float s_pv[2][QPB][DH];

    const float LOG2E = 1.4426950409f;

    // XCD-chunked swizzle: 64 consecutive qtile-blocks (one (b,h) slab) per XCD
    const int bid = (blockIdx.x & 7) * 64 + (blockIdx.x >> 3);
    const int b  = bid >> 8;
    const int h  = (bid >> 5) & 7;
    const int qt = bid & 31;
    const int qbase = qt * QPB;
    const int bh = b * NHEADS + h;
    const int t = threadIdx.x;
    const int Lv = vl[b];

    {   // stage eqf (direct copy) and wv (pre-scaled by -2)
        const int r = t >> 7, cc = (t & 127) * 4;
        *(float4*)&s_eq[r][cc] =
            *(const float4*)(eqf + ((size_t)(bh * LQL + qbase + r)) * DM + cc);
        s_wv2[t] = wv_a[t] * -2.0f;
    }
    __syncthreads();

    const int w = t >> 6, lane = t & 63;
    const int k  = w * 16 + (lane & 15);   // wave covers 16 consecutive k
    const int fq = lane >> 4;
    float acc[QPB] = {};
    if (k < Lv) {
        const unsigned short* kp = ekf + ((size_t)(bh * LKL + k)) * DM + fq * 128;
        uint4 kc = *(const uint4*)kp;      // 8 bf16
        #pragma unroll 1
        for (int it = 0; it < 16; ++it) {
            uint4 nx;
            if (it < 15) nx = *(const uint4*)(kp + 8);
            else         nx = kc;
            const float e0 = bflo(kc.x), e1 = bfhi(kc.x);
            const float e2 = bflo(kc.y), e3 = bfhi(kc.y);
            const float e4 = bflo(kc.z), e5 = bfhi(kc.z);
            const float e6 = bflo(kc.w), e7 = bfhi(kc.w);
            const int f0 = fq * 128 + it * 8;
            const float4 w0 = *(const float4*)&s_wv2[f0];
            const float4 w1 = *(const float4*)&s_wv2[f0 + 4];
            #pragma unroll
            for (int q = 0; q < QPB; ++q) {
                const float4 q0 = *(const float4*)&s_eq[q][f0];
                const float4 q1 = *(const float4*)&s_eq[q][f0 + 4];
                float a = acc[q];
                {   // pair (f0+0, f0+1)
                    const float pa = fmaf(e0, q0.x, 1.f);
                    const float pb = fmaf(e1, q0.y, 1.f);
                    const float nm = fmaf(w0.x, pb, w0.y * pa);
                    a = fmaf(nm, frcp(pa * pb), a);
                }
                {   // pair (f0+2, f0+3)
                    const float pa = fmaf(e2, q0.z, 1.f);
                    const float pb = fmaf(e3, q0.w, 1.f);
                    const float nm = fmaf(w0.z, pb, w0.w * pa);
                    a = fmaf(nm, frcp(pa * pb), a);
                }
                {   // pair (f0+4, f0+5)
                    const float pa = fmaf(e4, q1.x, 1.f);
                    const float pb = fmaf(e5, q1.y, 1.f);
                    const float nm = fmaf(w1.x, pb, w1.y * pa);
                    a = fmaf(nm, frcp(pa * pb), a);
                }
                {   // pair (f0+6, f0+7)
                    const float pa = fmaf(e6, q1.z, 1.f);
                    const float pb = fmaf(e7, q1.w, 1.f);
                    const float nm = fmaf(w1.z, pb, w1.w * pa);
                    a = fmaf(nm, frcp(pa * pb), a);
                }
                acc[q] = a;
            }
            kc = nx; kp += 8;
        }
    }
    // in-wave 4-way fq reduction: partials for k live in lanes {k,k+16,k+32,k+48}
    #pragma unroll
    for (int q = 0; q < QPB; ++q) {
        float a = acc[q];
        a += __shfl_xor(a, 16, 64);
        a += __shfl_xor(a, 32, 64);
        if (lane < 16) s_score[q][k] = a;
    }
    __syncthreads();

    if (t < 64 * QPB) {   // masked softmax: wave = q-row; lane covers k, k+64
        const int q = t >> 6, ln = t & 63;
        const float v0 = (ln < Lv)      ? s_score[q][ln]      : -3.0e38f;
        const float v1 = (ln + 64 < Lv) ? s_score[q][ln + 64] : -3.0e38f;
        float m = fmaxf(v0, v1);
        #pragma unroll
        for (int off = 32; off; off >>= 1) m = fmaxf(m, __shfl_xor(m, off, 64));
        const float e0 = fexp2((v0 - m) * LOG2E);
        const float e1 = fexp2((v1 - m) * LOG2E);
        float s = e0 + e1;
        #pragma unroll
        for (int off = 32; off; off >>= 1) s += __shfl_xor(s, off, 64);
        const float inv = frcp(s);
        s_attn[q][ln]      = e0 * inv;
        s_attn[q][ln + 64] = e1 * inv;
    }
    __syncthreads();

    {   // PV: thread (kh = t>>8, q = (t>>6)&3, d = t&63); only k < Lv
        const int d = t & 63, q = (t >> 6) & 3, kh = t >> 8;
        const float* vb = V + ((size_t)(b * LKL + kh * 64)) * DM + h * DH + d;
        int kmax = Lv - kh * 64;
        kmax = kmax < 0 ? 0 : (kmax > 64 ? 64 : kmax);
        float a0 = 0.f, a1 = 0.f, a2 = 0.f, a3 = 0.f;
        int kk = 0;
        for (; kk + 4 <= kmax; kk += 4) {
            a0 += s_attn[q][kh*64 + kk+0] * vb[(size_t)(kk+0) * DM];
            a1 += s_attn[q][kh*64 + kk+1] * vb[(size_t)(kk+1) * DM];
            a2 += s_attn[q][kh*64 + kk+2] * vb[(size_t)(kk+2) * DM];
            a3 += s_attn[q][kh*64 + kk+3] * vb[(size_t)(kk+3) * DM];
        }
        for (; kk < kmax; ++kk) a0 += s_attn[q][kh*64 + kk] * vb[(size_t)kk * DM];
        s_pv[kh][q][d] = (a0 + a1) + (a2 + a3);
    }
    __syncthreads();
    if (t < 64 * QPB) {
        const int q = t >> 6, d = t & 63;
        interh[((size_t)(b * LQL + qbase + q)) * DM + h * DH + d] =
            (_Float16)(s_pv[0][q][d] + s_pv[1][q][d]);
    }
}

// ---- Kernel 3: out = inter @ Wo^T, 32x32 tiles x 128 blocks ----------------
__global__ __launch_bounds__(256) void out_mfma(
    const _Float16* __restrict__ interh, const float* __restrict__ Wo,
    float* __restrict__ out)
{
    const int bm0 = blockIdx.y * 32, bn0 = blockIdx.x * 32;
    __shared__ _Float16 As[32][40];
    __shared__ _Float16 Ws[32][40];
    const int tid = threadIdx.x, wave = tid >> 6, lane = tid & 63;
    const int ms = wave & 1, ns = wave >> 1;       // 2x2 of 16x16 fragments
    const int srow = tid >> 3, sseg = tid & 7;     // 32 rows x 8 segs of 4
    const int fr = lane & 15, fg = (lane >> 4) * 8;

    v4f acc = {};
    for (int k0 = 0; k0 < DM; k0 += 32) {
        const v4h ha = *(const v4h*)(interh + (size_t)(bm0 + srow) * DM + k0 + sseg * 4);
        const float4 w4 = *(const float4*)(Wo + (size_t)(bn0 + srow) * DM + k0 + sseg * 4);
        __syncthreads();
        *(v4h*)&As[srow][sseg * 4] = ha;
        *(v4h*)&Ws[srow][sseg * 4] = cvt4(w4);
        __syncthreads();
        const v8h af = *(const v8h*)&As[ms * 16 + fr][fg];
        const v8h bf = *(const v8h*)&Ws[ns * 16 + fr][fg];
        acc = __builtin_amdgcn_mfma_f32_16x16x32_f16(af, bf, acc, 0, 0, 0);
    }
    #pragma unroll
    for (int rg = 0; rg < 4; ++rg) {
        const int row = bm0 + ms * 16 + (lane >> 4) * 4 + rg;
        const int col = bn0 + ns * 16 + fr;
        out[(size_t)row * DM + col] = acc[rg];
    }
}

extern "C" void kernel_launch(void* const* d_in, const int* in_sizes, int n_in,
                              void* d_out, int out_size, void* d_ws, size_t ws_size,
                              hipStream_t stream)
{
    const float* xq   = (const float*)d_in[0];
    const float* xk   = (const float*)d_in[1];
    const float* xv   = (const float*)d_in[2];
    const int*   vl   = (const int*)d_in[3];
    const float* Wq   = (const float*)d_in[4];
    const float* Wk   = (const float*)d_in[5];
    const float* Wv   = (const float*)d_in[6];
    const float* Wo   = (const float*)d_in[7];
    const float* Wqa  = (const float*)d_in[8];
    const float* Wka  = (const float*)d_in[9];
    const float* wv_a = (const float*)d_in[10];
    float* out = (float*)d_out;

    // ws carve (bytes): V 512K | eqf 4M | ekf 2M | interh 256K
    char* base = (char*)d_ws;
    float*          V      = (float*)         (base);
    float*          eqf    = (float*)         (base + 524288);
    unsigned short* ekf    = (unsigned short*)(base + 4718592);
    _Float16*       interh = (_Float16*)      (base + 6815744);

    qkvfeat_mfma<<<dim3(160), dim3(256), 0, stream>>>(
        xq, xk, xv, Wq, Wk, Wv, Wqa, Wka, vl, V, eqf, ekf);
    attn_kernel<<<dim3(512), dim3(512), 0, stream>>>(
        eqf, ekf, V, wv_a, vl, interh);
    out_mfma<<<dim3(16, 8), dim3(256), 0, stream>>>(interh, Wo, out);
}